// Round 6
// baseline (526.828 us; speedup 1.0000x reference)
//
#include <hip/hip_runtime.h>
#include <math.h>

static constexpr int N_NODES = 50000;
static constexpr int N_EDGES = 800000;
static constexpr int DMODEL  = 128;
static constexpr int MTILES  = N_NODES / 16;   // 3125 exactly

typedef __attribute__((ext_vector_type(8))) short short8;   // 8 bf16 (4 VGPRs)
typedef __attribute__((ext_vector_type(4))) float float4v;  // 4 fp32 acc

__device__ __forceinline__ unsigned short f2bf(float f) {
    unsigned u = __builtin_bit_cast(unsigned, f);
    u += 0x7fffu + ((u >> 16) & 1u);
    return (unsigned short)(u >> 16);
}
__device__ __forceinline__ float bflo(unsigned w) {   // low bf16 -> f32
    return __builtin_bit_cast(float, w << 16);
}
__device__ __forceinline__ float bfhi(unsigned w) {   // high bf16 -> f32
    return __builtin_bit_cast(float, w & 0xffff0000u);
}

// ---------------------------------------------------------------------------
// Weight prep: fp32 [K][N] row-major -> bf16 MFMA B-fragment order.
//   idx = (nt*ksteps + s)*512 + quad*128 + c*8 + j   (nt=n>>4, c=n&15, s=k>>5)
// Fused with edge histogram (saves a dispatch): blocks <3125 do hist.
// ---------------------------------------------------------------------------
struct PrepSeg { const float* src; int K; int N; int dstOff; };
struct PrepArgs { PrepSeg seg[13]; };

__global__ void hist_prep_kernel(const int* __restrict__ dst, int* counts, int E,
                                 PrepArgs pa, unsigned short* wf)
{
    int b = blockIdx.x;
    if (b < 3125) {
        int e = b * 256 + threadIdx.x;
        if (e < E) atomicAdd(&counts[dst[e]], 1);
    } else {
        int idx = b - 3125;
        PrepSeg sg = pa.seg[idx >> 7];
        int e = (idx & 127) * 256 + threadIdx.x;
        int total = sg.K * sg.N;
        if (e >= total) return;
        int n = e % sg.N;
        int k = e / sg.N;
        int ks = sg.K >> 5;
        int nt = n >> 4, c = n & 15, s = k >> 5, q = (k >> 3) & 3, jj = k & 7;
        int di = sg.dstOff + (nt * ks + s) * 512 + q * 128 + c * 8 + jj;
        wf[di] = f2bf(sg.src[e]);
    }
}

// ---------------------------------------------------------------------------
// LDS-free MFMA GEMM body, static grid-stride over 16-row m-tiles.
// (R4 lesson: atomic tile queues regress 2.5x; GX=391 grid-stride is balanced.)
// KVMODE: 0 = Cb[grow*ldC+col]; 1/2 = interleaved KV buffer, row = 512 B:
//   K elem -> row*256 + (col>>1)*4 + (col&1); V elem -> +2  (ushort units)
// EPI: 0=bias, 1=bias+relu, 2=bias+residual, 3=bias+residual+LayerNorm.
// ---------------------------------------------------------------------------
template<int KSTEPS, int NT, int EPI, bool AF32, bool WRF, bool WRB, int KVMODE>
__device__ __forceinline__ void gemm_body(
    const void* __restrict__ Ap, const unsigned short* __restrict__ Wfc,
    const float* __restrict__ bias, const float* res,
    float* Cf, unsigned short* Cb,
    const float* __restrict__ lnw, const float* __restrict__ lnb,
    int ldA, int ldC, int mtiles, int colBase)
{
    const int lane = threadIdx.x & 63;
    const int c = lane & 15;
    const int q = lane >> 4;

    short8 bfrag[NT][KSTEPS];
#pragma unroll
    for (int nt = 0; nt < NT; ++nt)
#pragma unroll
        for (int s = 0; s < KSTEPS; ++s)
            bfrag[nt][s] = *(const short8*)(Wfc + (nt * KSTEPS + s) * 512 + lane * 8);

    float bb[NT];
#pragma unroll
    for (int nt = 0; nt < NT; ++nt)
        bb[nt] = bias ? bias[colBase + nt * 16 + c] : 0.f;

    float lw[NT], lb[NT];
    if (EPI == 3) {
#pragma unroll
        for (int nt = 0; nt < NT; ++nt) {
            lw[nt] = lnw[nt * 16 + c];
            lb[nt] = lnb[nt * 16 + c];
        }
    }

    const int wid = blockIdx.x * 4 + (threadIdx.x >> 6);
    const int nw  = gridDim.x * 4;

    for (int mt = wid; mt < mtiles; mt += nw) {
        const int row0 = mt * 16;
        short8 afrag[KSTEPS];
        if (AF32) {
            const float* A32 = (const float*)Ap;
#pragma unroll
            for (int s = 0; s < KSTEPS; ++s) {
                const float4* p = (const float4*)(A32 + (size_t)(row0 + c) * ldA + s * 32 + q * 8);
                float4 x0 = p[0], x1 = p[1];
                short8 a;
                a[0] = (short)f2bf(x0.x); a[1] = (short)f2bf(x0.y);
                a[2] = (short)f2bf(x0.z); a[3] = (short)f2bf(x0.w);
                a[4] = (short)f2bf(x1.x); a[5] = (short)f2bf(x1.y);
                a[6] = (short)f2bf(x1.z); a[7] = (short)f2bf(x1.w);
                afrag[s] = a;
            }
        } else {
            const unsigned short* Ab = (const unsigned short*)Ap;
#pragma unroll
            for (int s = 0; s < KSTEPS; ++s)
                afrag[s] = *(const short8*)(Ab + (size_t)(row0 + c) * ldA + s * 32 + q * 8);
        }

        float4v acc[NT];
#pragma unroll
        for (int nt = 0; nt < NT; ++nt) acc[nt] = (float4v)0.f;
#pragma unroll
        for (int s = 0; s < KSTEPS; ++s)
#pragma unroll
            for (int nt = 0; nt < NT; ++nt)
                acc[nt] = __builtin_amdgcn_mfma_f32_16x16x32_bf16(afrag[s], bfrag[nt][s], acc[nt], 0, 0, 0);

        // epilogue: C row = row0 + q*4 + r, col = colBase + nt*16 + c
#pragma unroll
        for (int nt = 0; nt < NT; ++nt) {
            const int col = colBase + nt * 16 + c;
#pragma unroll
            for (int r = 0; r < 4; ++r) {
                const int grow = row0 + q * 4 + r;
                float v = acc[nt][r] + bb[nt];
                if (EPI == 2 || EPI == 3) v += res[(size_t)grow * ldC + col];
                if (EPI == 1) v = fmaxf(v, 0.f);
                acc[nt][r] = v;
            }
        }

        if (EPI == 3) {
#pragma unroll
            for (int r = 0; r < 4; ++r) {
                float s = 0.f, ss = 0.f;
#pragma unroll
                for (int nt = 0; nt < NT; ++nt) {
                    float v = acc[nt][r];
                    s += v; ss = fmaf(v, v, ss);
                }
#pragma unroll
                for (int o = 1; o < 16; o <<= 1) {
                    s  += __shfl_xor(s, o, 64);
                    ss += __shfl_xor(ss, o, 64);
                }
                float m   = s * (1.0f / 128.0f);
                float var = ss * (1.0f / 128.0f) - m * m;
                float rs  = rsqrtf(var + 1e-5f);
                const int grow = row0 + q * 4 + r;
#pragma unroll
                for (int nt = 0; nt < NT; ++nt) {
                    float v = (acc[nt][r] - m) * rs * lw[nt] + lb[nt];
                    if (WRF) Cf[(size_t)grow * ldC + nt * 16 + c] = v;
                    if (WRB) Cb[(size_t)grow * ldC + nt * 16 + c] = f2bf(v);
                }
            }
        } else {
#pragma unroll
            for (int nt = 0; nt < NT; ++nt) {
                const int col = colBase + nt * 16 + c;
#pragma unroll
                for (int r = 0; r < 4; ++r) {
                    const int grow = row0 + q * 4 + r;
                    if (WRF) Cf[(size_t)grow * ldC + col] = acc[nt][r];
                    if (WRB) {
                        size_t bi;
                        if (KVMODE == 0)
                            bi = (size_t)grow * ldC + col;
                        else
                            bi = (size_t)grow * 256 +
                                 (size_t)((col >> 1) * 4 + (col & 1) + (KVMODE == 2 ? 2 : 0));
                        Cb[bi] = f2bf(acc[nt][r]);
                    }
                }
            }
        }
    }
}

template<int KSTEPS, int NT, int EPI, bool AF32, bool WRF, bool WRB>
__global__ __launch_bounds__(256, 2)
void mfma_gemm(const void* __restrict__ Ap, const unsigned short* __restrict__ Wf,
               const float* __restrict__ bias, const float* res,
               float* Cf, unsigned short* Cb,
               const float* __restrict__ lnw, const float* __restrict__ lnb,
               int ldA, int ldC, int mtiles)
{
    const int colBase = blockIdx.y * NT * 16;
    const unsigned short* Wfc = Wf + (size_t)blockIdx.y * NT * KSTEPS * 512;
    gemm_body<KSTEPS, NT, EPI, AF32, WRF, WRB, 0>(
        Ap, Wfc, bias, res, Cf, Cb, lnw, lnb, ldA, ldC, mtiles, colBase);
}

// Q/K/V fused: blockIdx.y selects Q (normal layout) / K / V (interleaved KV).
struct QkvPtrs { const float* bias[3]; unsigned short* out[3]; };

__global__ __launch_bounds__(256, 2)
void qkv_gemm(const unsigned short* __restrict__ A, const unsigned short* __restrict__ WfBase,
              QkvPtrs ptrs, int mtiles)
{
    const int sel = blockIdx.y;
    const unsigned short* Wfc = WfBase + (size_t)sel * 32768;
    if (sel == 0)
        gemm_body<4, 8, 0, false, false, true, 0>(
            A, Wfc, ptrs.bias[0], nullptr, nullptr, ptrs.out[0], nullptr, nullptr,
            128, 128, mtiles, 0);
    else if (sel == 1)
        gemm_body<4, 8, 0, false, false, true, 1>(
            A, Wfc, ptrs.bias[1], nullptr, nullptr, ptrs.out[1], nullptr, nullptr,
            128, 128, mtiles, 0);
    else
        gemm_body<4, 8, 0, false, false, true, 2>(
            A, Wfc, ptrs.bias[2], nullptr, nullptr, ptrs.out[2], nullptr, nullptr,
            128, 128, mtiles, 0);
}

// ---------------------------------------------------------------------------
// FFN2 + residual + LN2 fused. K=256 (8 k-steps), NT=8 -> full 128-col rows.
// B streamed per k-step with explicit double-buffer prefetch. Epilogue stages
// the fp32 tile in per-wave LDS (stride 132: 2-way-free banks) and stores
// full 512 B lines; bf16 mirror read back from LDS (kills the 2x WRITE_SIZE
// inflation measured in R5). res aliases outF for layer 0 (per-row ownership).
// ---------------------------------------------------------------------------
__global__ __launch_bounds__(256, 2)
void ffn2_ln_gemm(const unsigned short* __restrict__ A, const unsigned short* __restrict__ Wf,
                  const float* __restrict__ bias, const float* res,
                  float* outF, unsigned short* outB,
                  const float* __restrict__ lnw, const float* __restrict__ lnb,
                  int mtiles)
{
    __shared__ float lsAll[4][16 * 132];
    const int wv   = threadIdx.x >> 6;
    const int lane = threadIdx.x & 63;
    const int c = lane & 15;
    const int q = lane >> 4;
    float* lsF = lsAll[wv];

    float bb[8], lw[8], lb[8];
#pragma unroll
    for (int nt = 0; nt < 8; ++nt) {
        bb[nt] = bias[nt * 16 + c];
        lw[nt] = lnw[nt * 16 + c];
        lb[nt] = lnb[nt * 16 + c];
    }

    const int wid = blockIdx.x * 4 + wv;
    const int nw  = gridDim.x * 4;

    for (int mt = wid; mt < mtiles; mt += nw) {
        const int row0 = mt * 16;
        short8 afrag[8];
#pragma unroll
        for (int s = 0; s < 8; ++s)
            afrag[s] = *(const short8*)(A + (size_t)(row0 + c) * 256 + s * 32 + q * 8);

        float4v acc[8];
#pragma unroll
        for (int nt = 0; nt < 8; ++nt) acc[nt] = (float4v)0.f;

        // B stream with double-buffer prefetch
        short8 bfr[8];
#pragma unroll
        for (int nt = 0; nt < 8; ++nt)
            bfr[nt] = *(const short8*)(Wf + (size_t)(nt * 8) * 512 + lane * 8);
#pragma unroll
        for (int s = 0; s < 8; ++s) {
            short8 nxt[8];
            if (s < 7) {
#pragma unroll
                for (int nt = 0; nt < 8; ++nt)
                    nxt[nt] = *(const short8*)(Wf + (size_t)(nt * 8 + s + 1) * 512 + lane * 8);
            }
#pragma unroll
            for (int nt = 0; nt < 8; ++nt)
                acc[nt] = __builtin_amdgcn_mfma_f32_16x16x32_bf16(afrag[s], bfr[nt], acc[nt], 0, 0, 0);
#pragma unroll
            for (int nt = 0; nt < 8; ++nt) bfr[nt] = nxt[nt];
        }

        // bias + residual
#pragma unroll
        for (int nt = 0; nt < 8; ++nt)
#pragma unroll
            for (int r = 0; r < 4; ++r) {
                const int grow = row0 + q * 4 + r;
                acc[nt][r] += bb[nt] + res[(size_t)grow * 128 + nt * 16 + c];
            }

        // row LayerNorm -> LDS stage
#pragma unroll
        for (int r = 0; r < 4; ++r) {
            float s = 0.f, ss = 0.f;
#pragma unroll
            for (int nt = 0; nt < 8; ++nt) {
                float v = acc[nt][r];
                s += v; ss = fmaf(v, v, ss);
            }
#pragma unroll
            for (int o = 1; o < 16; o <<= 1) {
                s  += __shfl_xor(s, o, 64);
                ss += __shfl_xor(ss, o, 64);
            }
            float m   = s * (1.0f / 128.0f);
            float var = ss * (1.0f / 128.0f) - m * m;
            float rs  = rsqrtf(var + 1e-5f);
#pragma unroll
            for (int nt = 0; nt < 8; ++nt)
                lsF[(q * 4 + r) * 132 + nt * 16 + c] = (acc[nt][r] - m) * rs * lw[nt] + lb[nt];
        }

        // coalesced fp32 store: 8 insts x (2 rows x 512 B full lines)
#pragma unroll
        for (int i = 0; i < 8; ++i) {
            int row = i * 2 + (lane >> 5);
            int cv  = (lane & 31) * 4;
            float4 v4 = *(float4*)&lsF[row * 132 + cv];
            *(float4*)(outF + (size_t)(row0 + row) * 128 + cv) = v4;
        }
        if (outB) {
#pragma unroll
            for (int i = 0; i < 4; ++i) {
                int row = i * 4 + (lane >> 4);
                int c0  = (lane & 15) * 8;
                float4 f0 = *(float4*)&lsF[row * 132 + c0];
                float4 f1 = *(float4*)&lsF[row * 132 + c0 + 4];
                int4 d;
                d.x = (int)((unsigned)f2bf(f0.x) | ((unsigned)f2bf(f0.y) << 16));
                d.y = (int)((unsigned)f2bf(f0.z) | ((unsigned)f2bf(f0.w) << 16));
                d.z = (int)((unsigned)f2bf(f1.x) | ((unsigned)f2bf(f1.y) << 16));
                d.w = (int)((unsigned)f2bf(f1.z) | ((unsigned)f2bf(f1.w) << 16));
                *(int4*)(outB + (size_t)(row0 + row) * 128 + c0) = d;
            }
        }
    }
}

// ---------------------------------------------------------------------------
// CSR build: hist (fused w/ prep) -> scan1 -> scan3 (inlines block-sum scan)
// -> scatter (offsets become segment ends).
// ---------------------------------------------------------------------------
__global__ __launch_bounds__(1024)
void scan1_kernel(const int* __restrict__ counts, int* offsets, int* blockSums, int N)
{
    __shared__ int sm[1024];
    int t = threadIdx.x;
    int i = blockIdx.x * 1024 + t;
    sm[t] = (i < N) ? counts[i] : 0;
    __syncthreads();
#pragma unroll
    for (int o = 1; o < 1024; o <<= 1) {
        int v = (t >= o) ? sm[t - o] : 0;
        __syncthreads();
        sm[t] += v;
        __syncthreads();
    }
    if (i < N) offsets[i + 1] = sm[t];
    if (t == 1023) blockSums[blockIdx.x] = sm[t];
}

__global__ __launch_bounds__(1024)
void scan3_kernel(int* offsets, const int* __restrict__ blockSums, int N, int nb)
{
    __shared__ int sOff;
    if (threadIdx.x < 64) {
        int t = threadIdx.x;
        int x = (t < nb) ? blockSums[t] : 0;
#pragma unroll
        for (int o = 1; o < 64; o <<= 1) {
            int v = __shfl_up(x, o, 64);
            if (t >= o) x += v;
        }
        int excl = (blockIdx.x == 0) ? 0 : __shfl(x, blockIdx.x - 1, 64);
        if (t == 0) sOff = excl;
    }
    __syncthreads();
    int i = blockIdx.x * 1024 + threadIdx.x;
    if (i < N) offsets[i + 1] += sOff;
    if (i == 0) offsets[0] = 0;
}

__global__ void scatter_kernel(const int* __restrict__ src, const int* __restrict__ dst,
                               int* offsets, int* esrc, int E)
{
    int e = blockIdx.x * 256 + threadIdx.x;
    if (e < E) {
        int d = dst[e];
        int pos = atomicAdd(&offsets[d], 1);
        esrc[pos] = src[e];
    }
}

// ---------------------------------------------------------------------------
// Attention aggregation, 4x unrolled, interleaved KV buffer: one 8 B gather
// per edge-lane yields (k-pair, v-pair). One wave per dst node; 8-lane
// shuffle reduce per head. attn may alias q (row n owned by wave n).
// ---------------------------------------------------------------------------
__global__ __launch_bounds__(256)
void agg_kernel(const unsigned short* qv, const unsigned short* __restrict__ kvt,
                const int* __restrict__ offsets, const int* __restrict__ esrc,
                unsigned short* attn, int n_nodes)
{
    int w    = (int)((blockIdx.x * 256 + threadIdx.x) >> 6);
    int lane = threadIdx.x & 63;
    if (w >= n_nodes) return;
    const unsigned lane4 = (unsigned)lane * 4u;
    const unsigned lane8 = (unsigned)lane * 8u;
    const char* kvc = (const char*)kvt;

    unsigned qb = *(const unsigned*)((const char*)qv + (((unsigned)w << 8) + lane4));
    float qx = bflo(qb), qy = bfhi(qb);
    int beg = (w == 0) ? 0 : offsets[w - 1];
    int end = offsets[w];
    float accx = 0.f, accy = 0.f, z = 0.f;
    const float SCL = 0.36067376022224085f;   // 0.25 * log2(e)

    for (int e = beg; e < end; e += 4) {
        int rem = end - e;
        unsigned o0 = ((unsigned)esrc[e] << 9) + lane8;
        unsigned o1 = ((unsigned)esrc[rem > 1 ? e + 1 : e] << 9) + lane8;
        unsigned o2 = ((unsigned)esrc[rem > 2 ? e + 2 : e] << 9) + lane8;
        unsigned o3 = ((unsigned)esrc[rem > 3 ? e + 3 : e] << 9) + lane8;
        uint2 a0 = *(const uint2*)(kvc + o0);
        uint2 a1 = *(const uint2*)(kvc + o1);
        uint2 a2 = *(const uint2*)(kvc + o2);
        uint2 a3 = *(const uint2*)(kvc + o3);

        float p0 = bflo(a0.x) * qx + bfhi(a0.x) * qy;
        float p1 = bflo(a1.x) * qx + bfhi(a1.x) * qy;
        float p2 = bflo(a2.x) * qx + bfhi(a2.x) * qy;
        float p3 = bflo(a3.x) * qx + bfhi(a3.x) * qy;
#pragma unroll
        for (int o = 1; o < 8; o <<= 1) {
            p0 += __shfl_xor(p0, o, 8);
            p1 += __shfl_xor(p1, o, 8);
            p2 += __shfl_xor(p2, o, 8);
            p3 += __shfl_xor(p3, o, 8);
        }
        float m1 = (rem > 1) ? 1.f : 0.f;
        float m2 = (rem > 2) ? 1.f : 0.f;
        float m3 = (rem > 3) ? 1.f : 0.f;
        float sv0 = exp2f(__builtin_amdgcn_fmed3f(p0, -20.f, 20.f) * SCL);
        float sv1 = exp2f(__builtin_amdgcn_fmed3f(p1, -20.f, 20.f) * SCL) * m1;
        float sv2 = exp2f(__builtin_amdgcn_fmed3f(p2, -20.f, 20.f) * SCL) * m2;
        float sv3 = exp2f(__builtin_amdgcn_fmed3f(p3, -20.f, 20.f) * SCL) * m3;

        accx = fmaf(sv0, bflo(a0.y), accx);
        accy = fmaf(sv0, bfhi(a0.y), accy);
        accx = fmaf(sv1, bflo(a1.y), accx);
        accy = fmaf(sv1, bfhi(a1.y), accy);
        accx = fmaf(sv2, bflo(a2.y), accx);
        accy = fmaf(sv2, bfhi(a2.y), accy);
        accx = fmaf(sv3, bflo(a3.y), accx);
        accy = fmaf(sv3, bfhi(a3.y), accy);
        z += sv0 + sv1 + sv2 + sv3;
    }
    float inv = 1.f / (z + 1e-6f);
    unsigned outw = (unsigned)f2bf(accx * inv) | ((unsigned)f2bf(accy * inv) << 16);
    *(unsigned*)((char*)attn + (((unsigned)w << 8) + lane4)) = outw;
}

// ---------------------------------------------------------------------------
extern "C" void kernel_launch(void* const* d_in, const int* in_sizes, int n_in,
                              void* d_out, int out_size, void* d_ws, size_t ws_size,
                              hipStream_t stream)
{
    const float* h_in  = (const float*)d_in[0];
    const int*   src   = (const int*)d_in[1];
    const int*   dst   = (const int*)d_in[2];
    const float* W_emb = (const float*)d_in[3];
    const float* Wq    = (const float*)d_in[4];
    const float* bq    = (const float*)d_in[5];
    const float* Wk    = (const float*)d_in[6];
    const float* bk    = (const float*)d_in[7];
    const float* Wv    = (const float*)d_in[8];
    const float* bv    = (const float*)d_in[9];
    const float* Wo    = (const float*)d_in[10];
    const float* bo    = (const float*)d_in[11];
    const float* ln1w  = (const float*)d_in[12];
    const float* ln1b  = (const float*)d_in[13];
    const float* Wf1   = (const float*)d_in[14];
    const float* bf1   = (const float*)d_in[15];
    const float* Wf2   = (const float*)d_in[16];
    const float* bf2   = (const float*)d_in[17];
    const float* ln2w  = (const float*)d_in[18];
    const float* ln2b  = (const float*)d_in[19];
    float* out = (float*)d_out;

    const int N = N_NODES, E = N_EDGES;
    const size_t NF = (size_t)N * DMODEL;

    float*          hbuf  = (float*)d_ws;                  // fp32 master h
    unsigned short* hbf   = (unsigned short*)(hbuf + NF);  // bf16 mirror
    unsigned short* qbuf  = hbf + NF;                      // q / attn
    unsigned short* kvbuf = qbuf + NF;                     // interleaved K/V [N][256]
    unsigned short* wf    = kvbuf + 2 * NF;                // frag-ordered weights
    int* offsets   = (int*)(wf + 278528);
    int* blockSums = offsets + (N + 1);
    int* counts    = blockSums + 64;
    int* esrc      = counts + N;
    unsigned short* fbuf = kvbuf;   // FFN hidden [N][256] aliases kvbuf (dead post-agg)

    const int EMB_O = 0, Q_O = 16384, O_O = 114688, F1_O = 147456, F2_O = 212992;
    // Q/K/V at Q_O + l*16384 + sel*32768 (K_O=49152, V_O=81920)

    const int edgeBlocks = (E + 255) / 256;     // 3125
    const int scanBlocks = (N + 1023) / 1024;   // 49
    const int rowBlocks  = (N + 3) / 4;
    const int GX = 391;   // 1564 waves x 2 tiles = 3128 >= 3125: balanced

    // ---- CSR build + weight prep (hist fused with prep) ----
    hipMemsetAsync(counts, 0, (size_t)N * sizeof(int), stream);
    PrepArgs pa;
    pa.seg[0]  = {W_emb,          128, 128, EMB_O};
    pa.seg[1]  = {Wq,             128, 128, Q_O};
    pa.seg[2]  = {Wq + 16384,     128, 128, Q_O + 16384};
    pa.seg[3]  = {Wk,             128, 128, 49152};
    pa.seg[4]  = {Wk + 16384,     128, 128, 49152 + 16384};
    pa.seg[5]  = {Wv,             128, 128, 81920};
    pa.seg[6]  = {Wv + 16384,     128, 128, 81920 + 16384};
    pa.seg[7]  = {Wo,             128, 128, O_O};
    pa.seg[8]  = {Wo + 16384,     128, 128, O_O + 16384};
    pa.seg[9]  = {Wf1,            128, 256, F1_O};
    pa.seg[10] = {Wf1 + 32768,    128, 256, F1_O + 32768};
    pa.seg[11] = {Wf2,            256, 128, F2_O};
    pa.seg[12] = {Wf2 + 32768,    256, 128, F2_O + 32768};
    hist_prep_kernel<<<edgeBlocks + 13 * 128, 256, 0, stream>>>(dst, counts, E, pa, wf);
    scan1_kernel<<<scanBlocks, 1024, 0, stream>>>(counts, offsets, blockSums, N);
    scan3_kernel<<<scanBlocks, 1024, 0, stream>>>(offsets, blockSums, N, scanBlocks);
    scatter_kernel<<<edgeBlocks, 256, 0, stream>>>(src, dst, offsets, esrc, E);

    // ---- embedding: h = h_in @ W_emb (fp32 A) -> hbuf + hbf ----
    mfma_gemm<4, 8, 0, true, true, true><<<dim3(GX, 1), 256, 0, stream>>>(
        h_in, wf + EMB_O, nullptr, nullptr, hbuf, hbf, nullptr, nullptr, 128, 128, MTILES);

    for (int l = 0; l < 2; ++l) {
        // Q (qbuf) + K/V (interleaved kvbuf) in one dispatch
        QkvPtrs qp;
        qp.bias[0] = bq + l * 128; qp.bias[1] = bk + l * 128; qp.bias[2] = bv + l * 128;
        qp.out[0] = qbuf; qp.out[1] = kvbuf; qp.out[2] = kvbuf;
        qkv_gemm<<<dim3(GX, 3), 256, 0, stream>>>(hbf, wf + Q_O + l * 16384, qp, MTILES);

        // attention aggregate (attn aliases qbuf)
        agg_kernel<<<rowBlocks, 256, 0, stream>>>(qbuf, kvbuf, offsets, esrc, qbuf, N);

        // hx = LN1(h + attn @ Wo + bo)  [fused GEMM+residual+LN] -> hbuf + hbf
        mfma_gemm<4, 8, 3, false, true, true><<<dim3(GX, 1), 256, 0, stream>>>(
            qbuf, wf + O_O + l * 16384, bo + l * 128, hbuf, hbuf, hbf,
            ln1w + l * 128, ln1b + l * 128, 128, 128, MTILES);

        // f1 = relu(hx @ Wf1 + bf1) -> bf16 [N,256] (aliases kvbuf)
        mfma_gemm<4, 8, 1, false, false, true><<<dim3(GX, 2), 256, 0, stream>>>(
            hbf, wf + F1_O + l * 32768, bf1 + l * 256, nullptr, nullptr, fbuf,
            nullptr, nullptr, 128, 256, MTILES);

        // h = LN2(hx + f1 @ Wf2 + bf2)  [fused] -> hbuf+hbf (l0) or out (l1)
        if (l == 0)
            ffn2_ln_gemm<<<dim3(GX, 1), 256, 0, stream>>>(
                fbuf, wf + F2_O, bf2, hbuf, hbuf, hbf, ln2w, ln2b, MTILES);
        else
            ffn2_ln_gemm<<<dim3(GX, 1), 256, 0, stream>>>(
                fbuf, wf + F2_O + 32768, bf2 + 128, hbuf, out, nullptr,
                ln2w + 128, ln2b + 128, MTILES);
    }
}

// Round 7
// 519.480 us; speedup vs baseline: 1.0141x; 1.0141x over previous
//
#include <hip/hip_runtime.h>
#include <math.h>

static constexpr int N_NODES = 50000;
static constexpr int N_EDGES = 800000;
static constexpr int DMODEL  = 128;
static constexpr int MTILES  = N_NODES / 16;   // 3125 exactly

typedef __attribute__((ext_vector_type(8))) short short8;      // 8 bf16 (4 VGPRs)
typedef __attribute__((ext_vector_type(4))) float float4v;     // 4 fp32 acc
typedef __attribute__((ext_vector_type(2))) _Float16 half2v;   // packed f16 pair

__device__ __forceinline__ unsigned short f2bf(float f) {
    unsigned u = __builtin_bit_cast(unsigned, f);
    u += 0x7fffu + ((u >> 16) & 1u);
    return (unsigned short)(u >> 16);
}
__device__ __forceinline__ unsigned short f2h(float f) {
    _Float16 h = (_Float16)f;                  // RNE
    return __builtin_bit_cast(unsigned short, h);
}
__device__ __forceinline__ float bflo(unsigned w) {   // low bf16 -> f32
    return __builtin_bit_cast(float, w << 16);
}
__device__ __forceinline__ float bfhi(unsigned w) {   // high bf16 -> f32
    return __builtin_bit_cast(float, w & 0xffff0000u);
}

// ---------------------------------------------------------------------------
// Weight prep: fp32 [K][N] row-major -> bf16 MFMA B-fragment order.
//   idx = (nt*ksteps + s)*512 + quad*128 + c*8 + j   (nt=n>>4, c=n&15, s=k>>5)
// Fused with edge histogram (saves a dispatch): blocks <3125 do hist.
// ---------------------------------------------------------------------------
struct PrepSeg { const float* src; int K; int N; int dstOff; };
struct PrepArgs { PrepSeg seg[13]; };

__global__ void hist_prep_kernel(const int* __restrict__ dst, int* counts, int E,
                                 PrepArgs pa, unsigned short* wf)
{
    int b = blockIdx.x;
    if (b < 3125) {
        int e = b * 256 + threadIdx.x;
        if (e < E) atomicAdd(&counts[dst[e]], 1);
    } else {
        int idx = b - 3125;
        PrepSeg sg = pa.seg[idx >> 7];
        int e = (idx & 127) * 256 + threadIdx.x;
        int total = sg.K * sg.N;
        if (e >= total) return;
        int n = e % sg.N;
        int k = e / sg.N;
        int ks = sg.K >> 5;
        int nt = n >> 4, c = n & 15, s = k >> 5, q = (k >> 3) & 3, jj = k & 7;
        int di = sg.dstOff + (nt * ks + s) * 512 + q * 128 + c * 8 + jj;
        wf[di] = f2bf(sg.src[e]);
    }
}

// ---------------------------------------------------------------------------
// LDS-free MFMA GEMM body, static grid-stride over 16-row m-tiles.
// R4 lesson: atomic tile queues regress 2.5x (GX=391 grid-stride is balanced).
// R6 lesson: scattered 2B epilogue stores (KV interleave) cost more than the
// merged agg gather saved — epilogue stores must stay contiguous.
// CVT: bf16 (0) or f16 (1) for the Cb output. EPI: 0=bias, 1=bias+relu,
// 2=bias+residual, 3=bias+residual+LayerNorm (NT*16==128, colBase==0).
// ---------------------------------------------------------------------------
template<int KSTEPS, int NT, int EPI, bool AF32, bool WRF, bool WRB, int CVT>
__device__ __forceinline__ void gemm_body(
    const void* __restrict__ Ap, const unsigned short* __restrict__ Wfc,
    const float* __restrict__ bias, const float* res,
    float* Cf, unsigned short* Cb,
    const float* __restrict__ lnw, const float* __restrict__ lnb,
    int ldA, int ldC, int mtiles, int colBase)
{
    const int lane = threadIdx.x & 63;
    const int c = lane & 15;
    const int q = lane >> 4;

    short8 bfrag[NT][KSTEPS];
#pragma unroll
    for (int nt = 0; nt < NT; ++nt)
#pragma unroll
        for (int s = 0; s < KSTEPS; ++s)
            bfrag[nt][s] = *(const short8*)(Wfc + (nt * KSTEPS + s) * 512 + lane * 8);

    float bb[NT];
#pragma unroll
    for (int nt = 0; nt < NT; ++nt)
        bb[nt] = bias ? bias[colBase + nt * 16 + c] : 0.f;

    float lw[NT], lb[NT];
    if (EPI == 3) {
#pragma unroll
        for (int nt = 0; nt < NT; ++nt) {
            lw[nt] = lnw[nt * 16 + c];
            lb[nt] = lnb[nt * 16 + c];
        }
    }

    const int wid = blockIdx.x * 4 + (threadIdx.x >> 6);
    const int nw  = gridDim.x * 4;

    for (int mt = wid; mt < mtiles; mt += nw) {
        const int row0 = mt * 16;
        short8 afrag[KSTEPS];
        if (AF32) {
            const float* A32 = (const float*)Ap;
#pragma unroll
            for (int s = 0; s < KSTEPS; ++s) {
                const float4* p = (const float4*)(A32 + (size_t)(row0 + c) * ldA + s * 32 + q * 8);
                float4 x0 = p[0], x1 = p[1];
                short8 a;
                a[0] = (short)f2bf(x0.x); a[1] = (short)f2bf(x0.y);
                a[2] = (short)f2bf(x0.z); a[3] = (short)f2bf(x0.w);
                a[4] = (short)f2bf(x1.x); a[5] = (short)f2bf(x1.y);
                a[6] = (short)f2bf(x1.z); a[7] = (short)f2bf(x1.w);
                afrag[s] = a;
            }
        } else {
            const unsigned short* Ab = (const unsigned short*)Ap;
#pragma unroll
            for (int s = 0; s < KSTEPS; ++s)
                afrag[s] = *(const short8*)(Ab + (size_t)(row0 + c) * ldA + s * 32 + q * 8);
        }

        float4v acc[NT];
#pragma unroll
        for (int nt = 0; nt < NT; ++nt) acc[nt] = (float4v)0.f;
#pragma unroll
        for (int s = 0; s < KSTEPS; ++s)
#pragma unroll
            for (int nt = 0; nt < NT; ++nt)
                acc[nt] = __builtin_amdgcn_mfma_f32_16x16x32_bf16(afrag[s], bfrag[nt][s], acc[nt], 0, 0, 0);

        // epilogue: C row = row0 + q*4 + r, col = colBase + nt*16 + c
#pragma unroll
        for (int nt = 0; nt < NT; ++nt) {
            const int col = colBase + nt * 16 + c;
#pragma unroll
            for (int r = 0; r < 4; ++r) {
                const int grow = row0 + q * 4 + r;
                float v = acc[nt][r] + bb[nt];
                if (EPI == 2 || EPI == 3) v += res[(size_t)grow * ldC + col];
                if (EPI == 1) v = fmaxf(v, 0.f);
                acc[nt][r] = v;
            }
        }

        if (EPI == 3) {
#pragma unroll
            for (int r = 0; r < 4; ++r) {
                float s = 0.f, ss = 0.f;
#pragma unroll
                for (int nt = 0; nt < NT; ++nt) {
                    float v = acc[nt][r];
                    s += v; ss = fmaf(v, v, ss);
                }
#pragma unroll
                for (int o = 1; o < 16; o <<= 1) {
                    s  += __shfl_xor(s, o, 64);
                    ss += __shfl_xor(ss, o, 64);
                }
                float m   = s * (1.0f / 128.0f);
                float var = ss * (1.0f / 128.0f) - m * m;
                float rs  = rsqrtf(var + 1e-5f);
                const int grow = row0 + q * 4 + r;
#pragma unroll
                for (int nt = 0; nt < NT; ++nt) {
                    float v = (acc[nt][r] - m) * rs * lw[nt] + lb[nt];
                    if (WRF) Cf[(size_t)grow * ldC + nt * 16 + c] = v;
                    if (WRB) Cb[(size_t)grow * ldC + nt * 16 + c] = f2bf(v);
                }
            }
        } else {
#pragma unroll
            for (int nt = 0; nt < NT; ++nt) {
                const int col = colBase + nt * 16 + c;
#pragma unroll
                for (int r = 0; r < 4; ++r) {
                    const int grow = row0 + q * 4 + r;
                    if (WRF) Cf[(size_t)grow * ldC + col] = acc[nt][r];
                    if (WRB) Cb[(size_t)grow * ldC + col] =
                        (CVT == 1) ? f2h(acc[nt][r]) : f2bf(acc[nt][r]);
                }
            }
        }
    }
}

template<int KSTEPS, int NT, int EPI, bool AF32, bool WRF, bool WRB>
__global__ __launch_bounds__(256, 2)
void mfma_gemm(const void* __restrict__ Ap, const unsigned short* __restrict__ Wf,
               const float* __restrict__ bias, const float* res,
               float* Cf, unsigned short* Cb,
               const float* __restrict__ lnw, const float* __restrict__ lnb,
               int ldA, int ldC, int mtiles)
{
    const int colBase = blockIdx.y * NT * 16;
    const unsigned short* Wfc = Wf + (size_t)blockIdx.y * NT * KSTEPS * 512;
    gemm_body<KSTEPS, NT, EPI, AF32, WRF, WRB, 0>(
        Ap, Wfc, bias, res, Cf, Cb, lnw, lnb, ldA, ldC, mtiles, colBase);
}

// Q/K/V fused: blockIdx.y selects weight block / bias / output.
// Q,K written as f16 (for agg's v_dot2); V as bf16.
struct QkvPtrs { const float* bias[3]; unsigned short* out[3]; };

__global__ __launch_bounds__(256, 2)
void qkv_gemm(const unsigned short* __restrict__ A, const unsigned short* __restrict__ WfBase,
              QkvPtrs ptrs, int mtiles)
{
    const int sel = blockIdx.y;
    const unsigned short* Wfc = WfBase + (size_t)sel * 32768;
    if (sel == 2)
        gemm_body<4, 8, 0, false, false, true, 0>(
            A, Wfc, ptrs.bias[2], nullptr, nullptr, ptrs.out[2], nullptr, nullptr,
            128, 128, mtiles, 0);
    else
        gemm_body<4, 8, 0, false, false, true, 1>(
            A, Wfc, ptrs.bias[sel], nullptr, nullptr, ptrs.out[sel], nullptr, nullptr,
            128, 128, mtiles, 0);
}

// ---------------------------------------------------------------------------
// FFN2 + residual + LN2 fused. K=256 (8 k-steps), NT=8 -> full 128-col rows.
// B streamed per k-step with double-buffer prefetch; LDS-staged epilogue.
// res aliases outF for layer 0 (per-row ownership: read-then-write, ok).
// ---------------------------------------------------------------------------
__global__ __launch_bounds__(256, 2)
void ffn2_ln_gemm(const unsigned short* __restrict__ A, const unsigned short* __restrict__ Wf,
                  const float* __restrict__ bias, const float* res,
                  float* outF, unsigned short* outB,
                  const float* __restrict__ lnw, const float* __restrict__ lnb,
                  int mtiles)
{
    __shared__ float lsAll[4][16 * 132];
    const int wv   = threadIdx.x >> 6;
    const int lane = threadIdx.x & 63;
    const int c = lane & 15;
    const int q = lane >> 4;
    float* lsF = lsAll[wv];

    float bb[8], lw[8], lb[8];
#pragma unroll
    for (int nt = 0; nt < 8; ++nt) {
        bb[nt] = bias[nt * 16 + c];
        lw[nt] = lnw[nt * 16 + c];
        lb[nt] = lnb[nt * 16 + c];
    }

    const int wid = blockIdx.x * 4 + wv;
    const int nw  = gridDim.x * 4;

    for (int mt = wid; mt < mtiles; mt += nw) {
        const int row0 = mt * 16;
        short8 afrag[8];
#pragma unroll
        for (int s = 0; s < 8; ++s)
            afrag[s] = *(const short8*)(A + (size_t)(row0 + c) * 256 + s * 32 + q * 8);

        float4v acc[8];
#pragma unroll
        for (int nt = 0; nt < 8; ++nt) acc[nt] = (float4v)0.f;

        short8 bfr[8];
#pragma unroll
        for (int nt = 0; nt < 8; ++nt)
            bfr[nt] = *(const short8*)(Wf + (size_t)(nt * 8) * 512 + lane * 8);
#pragma unroll
        for (int s = 0; s < 8; ++s) {
            short8 nxt[8];
            if (s < 7) {
#pragma unroll
                for (int nt = 0; nt < 8; ++nt)
                    nxt[nt] = *(const short8*)(Wf + (size_t)(nt * 8 + s + 1) * 512 + lane * 8);
            }
#pragma unroll
            for (int nt = 0; nt < 8; ++nt)
                acc[nt] = __builtin_amdgcn_mfma_f32_16x16x32_bf16(afrag[s], bfr[nt], acc[nt], 0, 0, 0);
#pragma unroll
            for (int nt = 0; nt < 8; ++nt) bfr[nt] = nxt[nt];
        }

#pragma unroll
        for (int nt = 0; nt < 8; ++nt)
#pragma unroll
            for (int r = 0; r < 4; ++r) {
                const int grow = row0 + q * 4 + r;
                acc[nt][r] += bb[nt] + res[(size_t)grow * 128 + nt * 16 + c];
            }

#pragma unroll
        for (int r = 0; r < 4; ++r) {
            float s = 0.f, ss = 0.f;
#pragma unroll
            for (int nt = 0; nt < 8; ++nt) {
                float v = acc[nt][r];
                s += v; ss = fmaf(v, v, ss);
            }
#pragma unroll
            for (int o = 1; o < 16; o <<= 1) {
                s  += __shfl_xor(s, o, 64);
                ss += __shfl_xor(ss, o, 64);
            }
            float m   = s * (1.0f / 128.0f);
            float var = ss * (1.0f / 128.0f) - m * m;
            float rs  = rsqrtf(var + 1e-5f);
#pragma unroll
            for (int nt = 0; nt < 8; ++nt)
                lsF[(q * 4 + r) * 132 + nt * 16 + c] = (acc[nt][r] - m) * rs * lw[nt] + lb[nt];
        }

#pragma unroll
        for (int i = 0; i < 8; ++i) {
            int row = i * 2 + (lane >> 5);
            int cv  = (lane & 31) * 4;
            float4 v4 = *(float4*)&lsF[row * 132 + cv];
            *(float4*)(outF + (size_t)(row0 + row) * 128 + cv) = v4;
        }
        if (outB) {
#pragma unroll
            for (int i = 0; i < 4; ++i) {
                int row = i * 4 + (lane >> 4);
                int c0  = (lane & 15) * 8;
                float4 f0 = *(float4*)&lsF[row * 132 + c0];
                float4 f1 = *(float4*)&lsF[row * 132 + c0 + 4];
                int4 d;
                d.x = (int)((unsigned)f2bf(f0.x) | ((unsigned)f2bf(f0.y) << 16));
                d.y = (int)((unsigned)f2bf(f0.z) | ((unsigned)f2bf(f0.w) << 16));
                d.z = (int)((unsigned)f2bf(f1.x) | ((unsigned)f2bf(f1.y) << 16));
                d.w = (int)((unsigned)f2bf(f1.z) | ((unsigned)f2bf(f1.w) << 16));
                *(int4*)(outB + (size_t)(row0 + row) * 128 + c0) = d;
            }
        }
    }
}

// ---------------------------------------------------------------------------
// CSR build: hist (fused w/ prep) -> scan1 -> scan3 (inlines block-sum scan)
// -> scatter (offsets become segment ends).
// ---------------------------------------------------------------------------
__global__ __launch_bounds__(1024)
void scan1_kernel(const int* __restrict__ counts, int* offsets, int* blockSums, int N)
{
    __shared__ int sm[1024];
    int t = threadIdx.x;
    int i = blockIdx.x * 1024 + t;
    sm[t] = (i < N) ? counts[i] : 0;
    __syncthreads();
#pragma unroll
    for (int o = 1; o < 1024; o <<= 1) {
        int v = (t >= o) ? sm[t - o] : 0;
        __syncthreads();
        sm[t] += v;
        __syncthreads();
    }
    if (i < N) offsets[i + 1] = sm[t];
    if (t == 1023) blockSums[blockIdx.x] = sm[t];
}

__global__ __launch_bounds__(1024)
void scan3_kernel(int* offsets, const int* __restrict__ blockSums, int N, int nb)
{
    __shared__ int sOff;
    if (threadIdx.x < 64) {
        int t = threadIdx.x;
        int x = (t < nb) ? blockSums[t] : 0;
#pragma unroll
        for (int o = 1; o < 64; o <<= 1) {
            int v = __shfl_up(x, o, 64);
            if (t >= o) x += v;
        }
        int excl = (blockIdx.x == 0) ? 0 : __shfl(x, blockIdx.x - 1, 64);
        if (t == 0) sOff = excl;
    }
    __syncthreads();
    int i = blockIdx.x * 1024 + threadIdx.x;
    if (i < N) offsets[i + 1] += sOff;
    if (i == 0) offsets[0] = 0;
}

__global__ void scatter_kernel(const int* __restrict__ src, const int* __restrict__ dst,
                               int* offsets, int* esrc, int E)
{
    int e = blockIdx.x * 256 + threadIdx.x;
    if (e < E) {
        int d = dst[e];
        int pos = atomicAdd(&offsets[d], 1);
        esrc[pos] = src[e];
    }
}

// ---------------------------------------------------------------------------
// Attention aggregation, 4x unrolled. Q,K are f16 -> per-edge dot is ONE
// v_dot2_f32_f16; V bf16 unpacked via shl/and. One wave per dst node; 8-lane
// shuffle reduce per head. attn (bf16) may alias q (row n owned by wave n).
// ---------------------------------------------------------------------------
__device__ __forceinline__ float dot2f(unsigned a, half2v b) {
#if __has_builtin(__builtin_amdgcn_fdot2)
    return __builtin_amdgcn_fdot2(__builtin_bit_cast(half2v, a), b, 0.f, false);
#else
    half2v av = __builtin_bit_cast(half2v, a);
    return (float)av[0] * (float)b[0] + (float)av[1] * (float)b[1];
#endif
}

__global__ __launch_bounds__(256)
void agg_kernel(const unsigned short* qv /*f16*/, const unsigned short* __restrict__ kv /*f16*/,
                const unsigned short* __restrict__ vv /*bf16*/,
                const int* __restrict__ offsets, const int* __restrict__ esrc,
                unsigned short* attn /*bf16*/, int n_nodes)
{
    int w    = (int)((blockIdx.x * 256 + threadIdx.x) >> 6);
    int lane = threadIdx.x & 63;
    if (w >= n_nodes) return;
    const unsigned lane4 = (unsigned)lane * 4u;
    const char* kvc = (const char*)kv;
    const char* vvc = (const char*)vv;

    unsigned qb = *(const unsigned*)((const char*)qv + (((unsigned)w << 8) + lane4));
    half2v q2 = __builtin_bit_cast(half2v, qb);
    int beg = (w == 0) ? 0 : offsets[w - 1];
    int end = offsets[w];
    float accx = 0.f, accy = 0.f, z = 0.f;
    const float SCL = 0.36067376022224085f;   // 0.25 * log2(e)

    for (int e = beg; e < end; e += 4) {
        int rem = end - e;
        unsigned o0 = ((unsigned)esrc[e] << 8) + lane4;
        unsigned o1 = ((unsigned)esrc[rem > 1 ? e + 1 : e] << 8) + lane4;
        unsigned o2 = ((unsigned)esrc[rem > 2 ? e + 2 : e] << 8) + lane4;
        unsigned o3 = ((unsigned)esrc[rem > 3 ? e + 3 : e] << 8) + lane4;
        unsigned kb0 = *(const unsigned*)(kvc + o0);
        unsigned kb1 = *(const unsigned*)(kvc + o1);
        unsigned kb2 = *(const unsigned*)(kvc + o2);
        unsigned kb3 = *(const unsigned*)(kvc + o3);
        unsigned vb0 = *(const unsigned*)(vvc + o0);
        unsigned vb1 = *(const unsigned*)(vvc + o1);
        unsigned vb2 = *(const unsigned*)(vvc + o2);
        unsigned vb3 = *(const unsigned*)(vvc + o3);

        float p0 = dot2f(kb0, q2);
        float p1 = dot2f(kb1, q2);
        float p2 = dot2f(kb2, q2);
        float p3 = dot2f(kb3, q2);
#pragma unroll
        for (int o = 1; o < 8; o <<= 1) {
            p0 += __shfl_xor(p0, o, 8);
            p1 += __shfl_xor(p1, o, 8);
            p2 += __shfl_xor(p2, o, 8);
            p3 += __shfl_xor(p3, o, 8);
        }
        float m1 = (rem > 1) ? 1.f : 0.f;
        float m2 = (rem > 2) ? 1.f : 0.f;
        float m3 = (rem > 3) ? 1.f : 0.f;
        float sv0 = exp2f(__builtin_amdgcn_fmed3f(p0, -20.f, 20.f) * SCL);
        float sv1 = exp2f(__builtin_amdgcn_fmed3f(p1, -20.f, 20.f) * SCL) * m1;
        float sv2 = exp2f(__builtin_amdgcn_fmed3f(p2, -20.f, 20.f) * SCL) * m2;
        float sv3 = exp2f(__builtin_amdgcn_fmed3f(p3, -20.f, 20.f) * SCL) * m3;

        accx = fmaf(sv0, bflo(vb0), accx);
        accy = fmaf(sv0, bfhi(vb0), accy);
        accx = fmaf(sv1, bflo(vb1), accx);
        accy = fmaf(sv1, bfhi(vb1), accy);
        accx = fmaf(sv2, bflo(vb2), accx);
        accy = fmaf(sv2, bfhi(vb2), accy);
        accx = fmaf(sv3, bflo(vb3), accx);
        accy = fmaf(sv3, bfhi(vb3), accy);
        z += sv0 + sv1 + sv2 + sv3;
    }
    float inv = 1.f / (z + 1e-6f);
    unsigned outw = (unsigned)f2bf(accx * inv) | ((unsigned)f2bf(accy * inv) << 16);
    *(unsigned*)((char*)attn + (((unsigned)w << 8) + lane4)) = outw;
}

// ---------------------------------------------------------------------------
extern "C" void kernel_launch(void* const* d_in, const int* in_sizes, int n_in,
                              void* d_out, int out_size, void* d_ws, size_t ws_size,
                              hipStream_t stream)
{
    const float* h_in  = (const float*)d_in[0];
    const int*   src   = (const int*)d_in[1];
    const int*   dst   = (const int*)d_in[2];
    const float* W_emb = (const float*)d_in[3];
    const float* Wq    = (const float*)d_in[4];
    const float* bq    = (const float*)d_in[5];
    const float* Wk    = (const float*)d_in[6];
    const float* bk    = (const float*)d_in[7];
    const float* Wv    = (const float*)d_in[8];
    const float* bv    = (const float*)d_in[9];
    const float* Wo    = (const float*)d_in[10];
    const float* bo    = (const float*)d_in[11];
    const float* ln1w  = (const float*)d_in[12];
    const float* ln1b  = (const float*)d_in[13];
    const float* Wf1   = (const float*)d_in[14];
    const float* bf1   = (const float*)d_in[15];
    const float* Wf2   = (const float*)d_in[16];
    const float* bf2   = (const float*)d_in[17];
    const float* ln2w  = (const float*)d_in[18];
    const float* ln2b  = (const float*)d_in[19];
    float* out = (float*)d_out;

    const int N = N_NODES, E = N_EDGES;
    const size_t NF = (size_t)N * DMODEL;

    float*          hbuf = (float*)d_ws;                  // fp32 master h
    unsigned short* hbf  = (unsigned short*)(hbuf + NF);  // bf16 mirror
    unsigned short* qbuf = hbf + NF;                      // q (f16) / attn (bf16)
    unsigned short* kbuf = qbuf + NF;                     // k (f16)
    unsigned short* vbuf = kbuf + NF;                     // v (bf16)
    unsigned short* wf   = vbuf + NF;                     // frag-ordered weights
    int* offsets   = (int*)(wf + 278528);
    int* blockSums = offsets + (N + 1);
    int* counts    = blockSums + 64;
    int* esrc      = counts + N;
    unsigned short* fbuf = kbuf;   // FFN hidden [N][256] spans kbuf+vbuf (dead post-agg)

    const int EMB_O = 0, Q_O = 16384, O_O = 114688, F1_O = 147456, F2_O = 212992;

    const int edgeBlocks = (E + 255) / 256;     // 3125
    const int scanBlocks = (N + 1023) / 1024;   // 49
    const int rowBlocks  = (N + 3) / 4;
    const int GX = 391;   // 1564 waves x 2 tiles = 3128 >= 3125: balanced

    // ---- CSR build + weight prep (hist fused with prep) ----
    hipMemsetAsync(counts, 0, (size_t)N * sizeof(int), stream);
    PrepArgs pa;
    pa.seg[0]  = {W_emb,          128, 128, EMB_O};
    pa.seg[1]  = {Wq,             128, 128, Q_O};
    pa.seg[2]  = {Wq + 16384,     128, 128, Q_O + 16384};
    pa.seg[3]  = {Wk,             128, 128, 49152};
    pa.seg[4]  = {Wk + 16384,     128, 128, 49152 + 16384};
    pa.seg[5]  = {Wv,             128, 128, 81920};
    pa.seg[6]  = {Wv + 16384,     128, 128, 81920 + 16384};
    pa.seg[7]  = {Wo,             128, 128, O_O};
    pa.seg[8]  = {Wo + 16384,     128, 128, O_O + 16384};
    pa.seg[9]  = {Wf1,            128, 256, F1_O};
    pa.seg[10] = {Wf1 + 32768,    128, 256, F1_O + 32768};
    pa.seg[11] = {Wf2,            256, 128, F2_O};
    pa.seg[12] = {Wf2 + 32768,    256, 128, F2_O + 32768};
    hist_prep_kernel<<<edgeBlocks + 13 * 128, 256, 0, stream>>>(dst, counts, E, pa, wf);
    scan1_kernel<<<scanBlocks, 1024, 0, stream>>>(counts, offsets, blockSums, N);
    scan3_kernel<<<scanBlocks, 1024, 0, stream>>>(offsets, blockSums, N, scanBlocks);
    scatter_kernel<<<edgeBlocks, 256, 0, stream>>>(src, dst, offsets, esrc, E);

    // ---- embedding: h = h_in @ W_emb (fp32 A) -> hbuf + hbf ----
    mfma_gemm<4, 8, 0, true, true, true><<<dim3(GX, 1), 256, 0, stream>>>(
        h_in, wf + EMB_O, nullptr, nullptr, hbuf, hbf, nullptr, nullptr, 128, 128, MTILES);

    for (int l = 0; l < 2; ++l) {
        // Q (f16), K (f16), V (bf16) in one dispatch
        QkvPtrs qp;
        qp.bias[0] = bq + l * 128; qp.bias[1] = bk + l * 128; qp.bias[2] = bv + l * 128;
        qp.out[0] = qbuf; qp.out[1] = kbuf; qp.out[2] = vbuf;
        qkv_gemm<<<dim3(GX, 3), 256, 0, stream>>>(hbf, wf + Q_O + l * 16384, qp, MTILES);

        // attention aggregate (attn bf16, aliases qbuf)
        agg_kernel<<<rowBlocks, 256, 0, stream>>>(qbuf, kbuf, vbuf, offsets, esrc, qbuf, N);

        // hx = LN1(h + attn @ Wo + bo)  [fused GEMM+residual+LN] -> hbuf + hbf
        mfma_gemm<4, 8, 3, false, true, true><<<dim3(GX, 1), 256, 0, stream>>>(
            qbuf, wf + O_O + l * 16384, bo + l * 128, hbuf, hbuf, hbf,
            ln1w + l * 128, ln1b + l * 128, 128, 128, MTILES);

        // f1 = relu(hx @ Wf1 + bf1) -> bf16 [N,256]
        mfma_gemm<4, 8, 1, false, false, true><<<dim3(GX, 2), 256, 0, stream>>>(
            hbf, wf + F1_O + l * 32768, bf1 + l * 256, nullptr, nullptr, fbuf,
            nullptr, nullptr, 128, 256, MTILES);

        // h = LN2(hx + f1 @ Wf2 + bf2)  [fused] -> hbuf+hbf (l0) or out (l1)
        if (l == 0)
            ffn2_ln_gemm<<<dim3(GX, 1), 256, 0, stream>>>(
                fbuf, wf + F2_O, bf2, hbuf, hbuf, hbf, ln2w, ln2b, MTILES);
        else
            ffn2_ln_gemm<<<dim3(GX, 1), 256, 0, stream>>>(
                fbuf, wf + F2_O + 32768, bf2 + 128, hbuf, out, nullptr,
                ln2w + 128, ln2b + 128, MTILES);
    }
}